// Round 5
// baseline (401.248 us; speedup 1.0000x reference)
//
#include <hip/hip_runtime.h>
#include <hip/hip_cooperative_groups.h>

namespace cg = cooperative_groups;

#define BATCH 16
#define HI 384
#define WI 384
#define CH 32
#define OUT_H 384
#define OUT_W 384
#define HW (HI * WI)          // 147456 pixels per image
#define GRID 1024             // cooperative grid: 4 blocks/CU * 256 CUs
#define SUBS (GRID / BATCH)   // 64 partial-sum blocks per batch image
#define NPIX (BATCH * OUT_H * OUT_W)      // 2359296 output pixels
#define NGID (NPIX * 8)                   // 18874368 thread-items (8/pixel)
#define GIDS_PER_BLK (NGID / GRID)        // 18432
#define REPS (GIDS_PER_BLK / 256)         // 72
#define PIX_PER_CHUNK (GIDS_PER_BLK / 8)  // 2304; 147456/2304=64 chunks/image

typedef float f32x4 __attribute__((ext_vector_type(4)));

// ---------------------------------------------------------------------------
// Shared device helpers (identical math in fused + fallback paths).
// Sampling matches reference exactly: floor -> weights from unclipped fracs,
// indices clipped to [0, 383].
// ---------------------------------------------------------------------------
__device__ __forceinline__ f32x4 sample_one(const f32x4* img, int ox, int oy,
                                            float th0, float th1, float th2,
                                            float th3, float th4, float th5,
                                            int c4) {
  const float gx = fmaf((float)ox, 2.0f / (float)(OUT_W - 1), -1.0f);
  const float gy = fmaf((float)oy, 2.0f / (float)(OUT_H - 1), -1.0f);
  const float sx = th0 * gx + th1 * gy + th2;
  const float sy = th3 * gx + th4 * gy + th5;
  const float x = (sx + 1.0f) * 0.5f * (float)(WI - 1);
  const float y = (sy + 1.0f) * 0.5f * (float)(HI - 1);

  const float x0f = floorf(x), y0f = floorf(y);
  const float wx1 = x - x0f, wx0 = 1.0f - wx1;
  const float wy1 = y - y0f, wy0 = 1.0f - wy1;
  const int x0 = min(max((int)x0f, 0), WI - 1);
  const int x1 = min(max((int)x0f + 1, 0), WI - 1);
  const int y0 = min(max((int)y0f, 0), HI - 1);
  const int y1 = min(max((int)y0f + 1, 0), HI - 1);

  const f32x4 g00 = img[((size_t)y0 * WI + x0) * 8 + c4];
  const f32x4 g01 = img[((size_t)y0 * WI + x1) * 8 + c4];
  const f32x4 g10 = img[((size_t)y1 * WI + x0) * 8 + c4];
  const f32x4 g11 = img[((size_t)y1 * WI + x1) * 8 + c4];

  return g00 * (wy0 * wx0) + g01 * (wy0 * wx1) + g10 * (wy1 * wx0) +
         g11 * (wy1 * wx1);
}

// ---------------------------------------------------------------------------
// Fused cooperative kernel. __launch_bounds__(256, 4): 4 waves/EU minimum
// -> VGPR capped at 128 -> 4 blocks/CU guaranteed -> 1024-block cooperative
// grid is provably co-resident (round-4 failure was an unchecked
// cooperative-launch-too-large).
// ---------------------------------------------------------------------------
__global__ __launch_bounds__(256, 4) void k_fused(
    const float* __restrict__ X, const float* __restrict__ Wl,
    const float* __restrict__ bl, float* __restrict__ out,
    float* __restrict__ ws) {
  cg::grid_group grid = cg::this_grid();
  const int t = threadIdx.x;
  const int blk = blockIdx.x;

  float* partials = ws;           // GRID * 32 floats
  float* theta = ws + GRID * CH;  // BATCH * 6 floats

  __shared__ f32x4 sh[256];
  __shared__ float feat[BATCH * CH];

  // ---- Phase A: partial sums (mean pass) ----
  {
    const int b = blk / SUBS;
    const int sub = blk % SUBS;
    const int c4 = t & 7;
    const int poff = t >> 3;
    const int ppb = HW / SUBS;  // 2304 pixels per block
    const int p0 = sub * ppb;

    const f32x4* base = (const f32x4*)(X + (size_t)b * HW * CH);
    f32x4 acc = {0.f, 0.f, 0.f, 0.f};
#pragma unroll 4
    for (int p = p0 + poff; p < p0 + ppb; p += 32) {
      acc += base[(size_t)p * 8 + c4];
    }
    sh[t] = acc;
    __syncthreads();
    if (t < 8) {
      f32x4 s = {0.f, 0.f, 0.f, 0.f};
      for (int i = 0; i < 32; ++i) s += sh[i * 8 + t];
      ((f32x4*)(partials + (size_t)blk * CH))[t] = s;
    }
  }

  grid.sync();

  // ---- Phase B: theta (block 0) ----
  if (blk == 0) {
    for (int k = t; k < BATCH * CH; k += 256) {
      const int b = k >> 5, c = k & 31;
      float s = 0.f;
      for (int i = 0; i < SUBS; ++i)
        s += partials[((size_t)b * SUBS + i) * CH + c];
      feat[k] = s * (1.0f / (float)HW);
    }
    __syncthreads();
    if (t < BATCH * 6) {
      const int b = t / 6, j = t % 6;
      float s = bl[j];
      for (int c = 0; c < CH; ++c) s += feat[b * CH + c] * Wl[c * 6 + j];
      theta[t] = s;
    }
  }

  grid.sync();

  // ---- Phase C: affine grid + bilinear sample ----
  {
    const int q = GRID >> 3;  // XCD-bijective chunk swizzle
    const int chunk = (blk & 7) * q + (blk >> 3);
    const int b = chunk / (HW / PIX_PER_CHUNK);  // one batch per chunk

    const float th0 = theta[b * 6 + 0], th1 = theta[b * 6 + 1],
                th2 = theta[b * 6 + 2], th3 = theta[b * 6 + 3],
                th4 = theta[b * 6 + 4], th5 = theta[b * 6 + 5];

    const f32x4* img = (const f32x4*)(X + (size_t)b * HW * CH);
    const int pbase = chunk * PIX_PER_CHUNK - b * (OUT_H * OUT_W);
    const int c4 = t & 7;

    for (int rep = 0; rep < REPS; ++rep) {
      const int gid = chunk * GIDS_PER_BLK + rep * 256 + t;
      const int lp = pbase + ((rep * 256 + t) >> 3);
      const int oy = lp / OUT_W;
      const int ox = lp % OUT_W;
      f32x4 r = sample_one(img, ox, oy, th0, th1, th2, th3, th4, th5, c4);
      __builtin_nontemporal_store(r, &((f32x4*)out)[gid]);
    }
  }
}

// ---------------------------------------------------------------------------
// Fallback path: the round-3-verified 3-kernel pipeline (same partials
// layout: 1024 blocks, SUBS per batch).
// ---------------------------------------------------------------------------
__global__ __launch_bounds__(256) void k_partial_sums(
    const float* __restrict__ X, float* __restrict__ partials) {
  const int blk = blockIdx.x;
  const int b = blk / SUBS;
  const int sub = blk % SUBS;
  const int t = threadIdx.x;
  const int c4 = t & 7;
  const int poff = t >> 3;
  const int ppb = HW / SUBS;
  const int p0 = sub * ppb;

  const f32x4* base = (const f32x4*)(X + (size_t)b * HW * CH);
  f32x4 acc = {0.f, 0.f, 0.f, 0.f};
#pragma unroll 4
  for (int p = p0 + poff; p < p0 + ppb; p += 32) {
    acc += base[(size_t)p * 8 + c4];
  }
  __shared__ f32x4 sh[256];
  sh[t] = acc;
  __syncthreads();
  if (t < 8) {
    f32x4 s = {0.f, 0.f, 0.f, 0.f};
    for (int i = 0; i < 32; ++i) s += sh[i * 8 + t];
    ((f32x4*)(partials + (size_t)blk * CH))[t] = s;
  }
}

__global__ __launch_bounds__(512) void k_theta(
    const float* __restrict__ partials, const float* __restrict__ Wl,
    const float* __restrict__ bl, float* __restrict__ theta) {
  __shared__ float feat[BATCH * CH];
  const int t = threadIdx.x;
  {
    const int b = t >> 5, c = t & 31;
    float s = 0.f;
    for (int i = 0; i < SUBS; ++i)
      s += partials[((size_t)b * SUBS + i) * CH + c];
    feat[t] = s * (1.0f / (float)HW);
  }
  __syncthreads();
  if (t < BATCH * 6) {
    const int b = t / 6, j = t % 6;
    float s = bl[j];
    for (int c = 0; c < CH; ++c) s += feat[b * CH + c] * Wl[c * 6 + j];
    theta[t] = s;
  }
}

__global__ __launch_bounds__(256) void k_sample(
    const float* __restrict__ X, const float* __restrict__ theta,
    float* __restrict__ out) {
  const int q = gridDim.x >> 3;
  const int bid = blockIdx.x;
  const int blk = (bid & 7) * q + (bid >> 3);

  const int gid = blk * 256 + threadIdx.x;
  const int c4 = gid & 7;
  const int n = gid >> 3;
  const int b = n / (OUT_H * OUT_W);
  const int p = n % (OUT_H * OUT_W);
  const int oy = p / OUT_W;
  const int ox = p % OUT_W;

  const float* th = theta + b * 6;
  const f32x4* img = (const f32x4*)(X + (size_t)b * HW * CH);
  f32x4 r = sample_one(img, ox, oy, th[0], th[1], th[2], th[3], th[4], th[5],
                       c4);
  __builtin_nontemporal_store(r, &((f32x4*)out)[gid]);
}

extern "C" void kernel_launch(void* const* d_in, const int* in_sizes, int n_in,
                              void* d_out, int out_size, void* d_ws,
                              size_t ws_size, hipStream_t stream) {
  const float* X = (const float*)d_in[0];
  const float* Wl = (const float*)d_in[1];
  const float* bl = (const float*)d_in[2];
  float* out = (float*)d_out;
  float* ws = (float*)d_ws;

  void* args[] = {(void*)&X, (void*)&Wl, (void*)&bl, (void*)&out, (void*)&ws};
  hipError_t err = hipLaunchCooperativeKernel((void*)k_fused, dim3(GRID),
                                              dim3(256), args, 0, stream);
  if (err != hipSuccess) {
    // Deterministic fallback: round-3-verified 3-kernel pipeline.
    float* partials = ws;
    float* theta = ws + GRID * CH;
    k_partial_sums<<<GRID, 256, 0, stream>>>(X, partials);
    k_theta<<<1, 512, 0, stream>>>(partials, Wl, bl, theta);
    k_sample<<<NGID / 256, 256, 0, stream>>>(X, theta, out);
  }
}

// Round 6
// 180.675 us; speedup vs baseline: 2.2208x; 2.2208x over previous
//
#include <hip/hip_runtime.h>

#define BATCH 16
#define HI 384
#define WI 384
#define CH 32
#define OUT_H 384
#define OUT_W 384
#define HW (HI * WI)
#define NBLK 64                        // partial-sum blocks per batch image
#define NPIX (BATCH * OUT_H * OUT_W)   // 2359296 output pixels
#define NT4 (NPIX * 4)                 // 4 threads per pixel
#define SAMP_BLOCKS (NT4 / 256)        // 36864, divisible by 8

typedef float f32x4 __attribute__((ext_vector_type(4)));

// ---------------------------------------------------------------------------
// Kernel 1: per-(batch, slice) partial sums (mean pass). Each block owns
// (b, sub) and writes its own 32-float partial vector — no atomics, fully
// deterministic. A wave reads 8 consecutive pixels * 128B = 1KB contiguous.
// Normal (cache-allocating) loads on purpose: warms L2/L3 with X for the
// gather phase (measured round 5: gather HBM fetch drops to ~141MB).
// ---------------------------------------------------------------------------
__global__ __launch_bounds__(256) void k_partial_sums(
    const float* __restrict__ X, float* __restrict__ partials) {
  const int blk = blockIdx.x;  // [0, BATCH*NBLK)
  const int b = blk / NBLK;
  const int sub = blk % NBLK;
  const int t = threadIdx.x;
  const int c4 = t & 7;
  const int poff = t >> 3;               // 0..31
  const int ppb = HW / NBLK;             // 2304
  const int p0 = sub * ppb;

  const f32x4* base = (const f32x4*)(X + (size_t)b * HW * CH);
  f32x4 acc = {0.f, 0.f, 0.f, 0.f};
#pragma unroll 4
  for (int p = p0 + poff; p < p0 + ppb; p += 32) {
    acc += base[(size_t)p * 8 + c4];
  }

  __shared__ f32x4 sh[256];
  sh[t] = acc;
  __syncthreads();
  if (t < 8) {
    f32x4 s = {0.f, 0.f, 0.f, 0.f};
    for (int i = 0; i < 32; ++i) s += sh[i * 8 + t];
    ((f32x4*)(partials + (size_t)blk * CH))[t] = s;
  }
}

// ---------------------------------------------------------------------------
// Kernel 2: reduce partials -> feat [B,32], then theta = feat@W + b.
// ---------------------------------------------------------------------------
__global__ __launch_bounds__(512) void k_theta(
    const float* __restrict__ partials, const float* __restrict__ Wl,
    const float* __restrict__ bl, float* __restrict__ theta) {
  __shared__ float feat[BATCH * CH];  // 512
  const int t = threadIdx.x;
  {
    const int b = t >> 5, c = t & 31;
    float s = 0.f;
    for (int i = 0; i < NBLK; ++i)
      s += partials[((size_t)b * NBLK + i) * CH + c];
    feat[t] = s * (1.0f / (float)HW);
  }
  __syncthreads();
  if (t < BATCH * 6) {
    const int b = t / 6, j = t % 6;
    float s = bl[j];
    for (int c = 0; c < CH; ++c) s += feat[b * CH + c] * Wl[c * 6 + j];
    theta[t] = s;
  }
}

// ---------------------------------------------------------------------------
// Kernel 3: affine grid + bilinear sample. 4 threads per output pixel; each
// thread covers 8 channels = 2 x f32x4 per tap -> issues 8 INDEPENDENT 16B
// gather loads before any consume (2x the in-flight bytes of the round-3
// version; fixes the latency-boundness measured in round 5's fused kernel:
// VALUBusy 6.7%, 1.67TB/s). Per tap a 4-lane cluster still fetches one
// contiguous 128B segment; output is 128B-coalesced NT stores (keep L2/L3
// for the gather).
// XCD swizzle keeps adjacent output rows (sharing source rows) on one XCD L2.
// Math matches reference exactly: floor -> weights from unclipped fracs,
// indices clipped to [0, 383].
// ---------------------------------------------------------------------------
__global__ __launch_bounds__(256) void k_sample(
    const float* __restrict__ X, const float* __restrict__ theta,
    float* __restrict__ out) {
  // bijective XCD swizzle (gridDim.x = 36864, divisible by 8)
  const int q = SAMP_BLOCKS >> 3;
  const int bid = blockIdx.x;
  const int blk = (bid & 7) * q + (bid >> 3);

  const int gid = blk * 256 + threadIdx.x;  // < 9.44M
  const int c2 = gid & 3;                   // which 8-channel slice
  const int n = gid >> 2;                   // output pixel index
  const int b = n / (OUT_H * OUT_W);
  const int p = n % (OUT_H * OUT_W);
  const int oy = p / OUT_W;
  const int ox = p % OUT_W;

  const float* th = theta + b * 6;
  const float gx = fmaf((float)ox, 2.0f / (float)(OUT_W - 1), -1.0f);
  const float gy = fmaf((float)oy, 2.0f / (float)(OUT_H - 1), -1.0f);
  const float sx = th[0] * gx + th[1] * gy + th[2];
  const float sy = th[3] * gx + th[4] * gy + th[5];
  const float x = (sx + 1.0f) * 0.5f * (float)(WI - 1);
  const float y = (sy + 1.0f) * 0.5f * (float)(HI - 1);

  const float x0f = floorf(x), y0f = floorf(y);
  const float wx1 = x - x0f, wx0 = 1.0f - wx1;
  const float wy1 = y - y0f, wy0 = 1.0f - wy1;
  const int x0 = min(max((int)x0f, 0), WI - 1);
  const int x1 = min(max((int)x0f + 1, 0), WI - 1);
  const int y0 = min(max((int)y0f, 0), HI - 1);
  const int y1 = min(max((int)y0f + 1, 0), HI - 1);

  const f32x4* img = (const f32x4*)(X + (size_t)b * HW * CH);
  const size_t s00 = ((size_t)y0 * WI + x0) * 8 + c2 * 2;
  const size_t s01 = ((size_t)y0 * WI + x1) * 8 + c2 * 2;
  const size_t s10 = ((size_t)y1 * WI + x0) * 8 + c2 * 2;
  const size_t s11 = ((size_t)y1 * WI + x1) * 8 + c2 * 2;

  // 8 independent loads issued back-to-back (compiler schedules them ahead
  // of the FMA chain; ~128B in flight per thread).
  const f32x4 a00 = img[s00], b00 = img[s00 + 1];
  const f32x4 a01 = img[s01], b01 = img[s01 + 1];
  const f32x4 a10 = img[s10], b10 = img[s10 + 1];
  const f32x4 a11 = img[s11], b11 = img[s11 + 1];

  const float w00 = wy0 * wx0, w01 = wy0 * wx1;
  const float w10 = wy1 * wx0, w11 = wy1 * wx1;

  const f32x4 r0 = a00 * w00 + a01 * w01 + a10 * w10 + a11 * w11;
  const f32x4 r1 = b00 * w00 + b01 * w01 + b10 * w10 + b11 * w11;

  f32x4* dst = (f32x4*)out + ((size_t)n * 8 + c2 * 2);
  __builtin_nontemporal_store(r0, dst);
  __builtin_nontemporal_store(r1, dst + 1);
}

extern "C" void kernel_launch(void* const* d_in, const int* in_sizes, int n_in,
                              void* d_out, int out_size, void* d_ws,
                              size_t ws_size, hipStream_t stream) {
  const float* X = (const float*)d_in[0];
  const float* Wl = (const float*)d_in[1];
  const float* bl = (const float*)d_in[2];
  float* out = (float*)d_out;

  float* partials = (float*)d_ws;                       // BATCH*NBLK*CH floats
  float* theta = partials + (size_t)BATCH * NBLK * CH;  // BATCH*6 floats

  k_partial_sums<<<BATCH * NBLK, 256, 0, stream>>>(X, partials);
  k_theta<<<1, 512, 0, stream>>>(partials, Wl, bl, theta);
  k_sample<<<SAMP_BLOCKS, 256, 0, stream>>>(X, theta, out);
}

// Round 7
// 173.494 us; speedup vs baseline: 2.3128x; 1.0414x over previous
//
#include <hip/hip_runtime.h>

#define BATCH 16
#define HI 384
#define WI 384
#define CH 32
#define OUT_H 384
#define OUT_W 384
#define HW (HI * WI)
#define NBLK 128                       // partial-sum blocks per batch image
#define NPIX (BATCH * OUT_H * OUT_W)   // 2359296 output pixels
#define TILE_W 8
#define TILE_H 4
#define TILES_X (OUT_W / TILE_W)       // 48
#define TILES_Y (OUT_H / TILE_H)       // 96
#define TILES_PER_IMG (TILES_X * TILES_Y)       // 4608
#define SAMP_BLOCKS (BATCH * TILES_PER_IMG)     // 73728, divisible by 8

typedef float f32x4 __attribute__((ext_vector_type(4)));

// ---------------------------------------------------------------------------
// Kernel 1: per-(batch, slice) partial sums (mean pass). Each block owns
// (b, sub) and writes its own 32-float partial vector — no atomics,
// deterministic. A wave reads 8 consecutive pixels * 128B = 1KB contiguous.
// NBLK=128 -> 2048 blocks = 8 blocks/CU for better balance/latency hiding.
// Normal (cache-allocating) loads on purpose: warms L2/L3 with X for the
// gather phase (round-5 counters: gather HBM fetch only ~141MB).
// ---------------------------------------------------------------------------
__global__ __launch_bounds__(256) void k_partial_sums(
    const float* __restrict__ X, float* __restrict__ partials) {
  const int blk = blockIdx.x;  // [0, BATCH*NBLK)
  const int b = blk / NBLK;
  const int sub = blk % NBLK;
  const int t = threadIdx.x;
  const int c4 = t & 7;
  const int poff = t >> 3;     // 0..31
  const int ppb = HW / NBLK;   // 1152
  const int p0 = sub * ppb;

  const f32x4* base = (const f32x4*)(X + (size_t)b * HW * CH);
  f32x4 acc = {0.f, 0.f, 0.f, 0.f};
#pragma unroll 4
  for (int p = p0 + poff; p < p0 + ppb; p += 32) {
    acc += base[(size_t)p * 8 + c4];
  }

  __shared__ f32x4 sh[256];
  sh[t] = acc;
  __syncthreads();
  if (t < 8) {
    f32x4 s = {0.f, 0.f, 0.f, 0.f};
    for (int i = 0; i < 32; ++i) s += sh[i * 8 + t];
    ((f32x4*)(partials + (size_t)blk * CH))[t] = s;
  }
}

// ---------------------------------------------------------------------------
// Kernel 2: reduce partials -> feat [B,32], then theta = feat@W + b.
// 512 threads: thread t = (b, c); i-loads are independent -> pipelined.
// ---------------------------------------------------------------------------
__global__ __launch_bounds__(512) void k_theta(
    const float* __restrict__ partials, const float* __restrict__ Wl,
    const float* __restrict__ bl, float* __restrict__ theta) {
  __shared__ float feat[BATCH * CH];  // 512
  const int t = threadIdx.x;
  {
    const int b = t >> 5, c = t & 31;
    float s = 0.f;
#pragma unroll 8
    for (int i = 0; i < NBLK; ++i)
      s += partials[((size_t)b * NBLK + i) * CH + c];
    feat[t] = s * (1.0f / (float)HW);
  }
  __syncthreads();
  if (t < BATCH * 6) {
    const int b = t / 6, j = t % 6;
    float s = bl[j];
    for (int c = 0; c < CH; ++c) s += feat[b * CH + c] * Wl[c * 6 + j];
    theta[t] = s;
  }
}

// ---------------------------------------------------------------------------
// Kernel 3: affine grid + bilinear sample, 2D-TILED pixel mapping.
// Block = one 8x4 output tile (32 pixels), 8 threads/pixel (c4 = t&7),
// wave w = tile row w. Vertical tap reuse (row r's y1 == row r+1's y0) is
// now captured IN-L1 by co-resident waves of the same block (was: cross-
// block, time-separated, L2-only). Tiles ordered column-major within an
// image so consecutive blocks -- same XCD after the bijective swizzle --
// are vertically adjacent: tile-boundary row reuse stays in that XCD's L2.
// Per-wave coalescing unchanged: each tap load = 8px x 128B ~ 1KB segment;
// store = 1KB contiguous NT (keep L2/L3 for the gather).
// Math matches reference exactly: floor -> weights from unclipped fracs,
// indices clipped to [0, 383].
// ---------------------------------------------------------------------------
__global__ __launch_bounds__(256) void k_sample(
    const float* __restrict__ X, const float* __restrict__ theta,
    float* __restrict__ out) {
  // bijective XCD swizzle (gridDim.x = 73728, divisible by 8)
  const int q = SAMP_BLOCKS >> 3;
  const int bid = blockIdx.x;
  const int blk = (bid & 7) * q + (bid >> 3);

  const int b = blk / TILES_PER_IMG;
  const int tl = blk % TILES_PER_IMG;
  const int tx = tl / TILES_Y;  // column-major: consecutive blk -> ty+1
  const int ty = tl % TILES_Y;

  const int t = threadIdx.x;
  const int c4 = t & 7;
  const int px = t >> 3;        // 0..31
  const int col = px & 7;       // 0..7
  const int row = px >> 3;      // 0..3 (== wave id)

  const int ox = tx * TILE_W + col;
  const int oy = ty * TILE_H + row;

  const float* th = theta + b * 6;
  const float gx = fmaf((float)ox, 2.0f / (float)(OUT_W - 1), -1.0f);
  const float gy = fmaf((float)oy, 2.0f / (float)(OUT_H - 1), -1.0f);
  const float sx = th[0] * gx + th[1] * gy + th[2];
  const float sy = th[3] * gx + th[4] * gy + th[5];
  const float x = (sx + 1.0f) * 0.5f * (float)(WI - 1);
  const float y = (sy + 1.0f) * 0.5f * (float)(HI - 1);

  const float x0f = floorf(x), y0f = floorf(y);
  const float wx1 = x - x0f, wx0 = 1.0f - wx1;
  const float wy1 = y - y0f, wy0 = 1.0f - wy1;
  const int x0 = min(max((int)x0f, 0), WI - 1);
  const int x1 = min(max((int)x0f + 1, 0), WI - 1);
  const int y0 = min(max((int)y0f, 0), HI - 1);
  const int y1 = min(max((int)y0f + 1, 0), HI - 1);

  const f32x4* img = (const f32x4*)(X + (size_t)b * HW * CH);
  const f32x4 g00 = img[((size_t)y0 * WI + x0) * 8 + c4];
  const f32x4 g01 = img[((size_t)y0 * WI + x1) * 8 + c4];
  const f32x4 g10 = img[((size_t)y1 * WI + x0) * 8 + c4];
  const f32x4 g11 = img[((size_t)y1 * WI + x1) * 8 + c4];

  const float w00 = wy0 * wx0, w01 = wy0 * wx1;
  const float w10 = wy1 * wx0, w11 = wy1 * wx1;

  const f32x4 r = g00 * w00 + g01 * w01 + g10 * w10 + g11 * w11;

  const size_t n = (size_t)b * (OUT_H * OUT_W) + (size_t)oy * OUT_W + ox;
  __builtin_nontemporal_store(r, (f32x4*)out + n * 8 + c4);
}

extern "C" void kernel_launch(void* const* d_in, const int* in_sizes, int n_in,
                              void* d_out, int out_size, void* d_ws,
                              size_t ws_size, hipStream_t stream) {
  const float* X = (const float*)d_in[0];
  const float* Wl = (const float*)d_in[1];
  const float* bl = (const float*)d_in[2];
  float* out = (float*)d_out;

  float* partials = (float*)d_ws;                       // BATCH*NBLK*CH floats
  float* theta = partials + (size_t)BATCH * NBLK * CH;  // BATCH*6 floats

  k_partial_sums<<<BATCH * NBLK, 256, 0, stream>>>(X, partials);
  k_theta<<<1, 512, 0, stream>>>(partials, Wl, bl, theta);
  k_sample<<<SAMP_BLOCKS, 256, 0, stream>>>(X, theta, out);
}